// Round 6
// baseline (353.564 us; speedup 1.0000x reference)
//
#include <hip/hip_runtime.h>
#include <hip/hip_bf16.h>

typedef _Float16 f16;
typedef _Float16 f16x8 __attribute__((ext_vector_type(8)));
typedef float f32x4 __attribute__((ext_vector_type(4)));

#define NN 200000
#define KK 512
#define CC 64
#define JJ 32
#define REPS 3  /* DIAGNOSTIC: repeat identical work to surface gmm_main in rocprof top-5 */
// W_frag: 48 F-ksteps (16 w1 | 16 wh | 16 wl) x 4 coltiles x 64 lanes x 8 f16
#define WFRAG_ELEMS (48 * 4 * 64 * 8) /* 98304 f16 = 192 KiB */

__device__ inline void gload_lds16(const void* g, void* l) {
  __builtin_amdgcn_global_load_lds(
      (const __attribute__((address_space(1))) void*)g,
      (__attribute__((address_space(3))) void*)l, 16, 0, 0);
}

__device__ inline f32x4 ntl(const float* p) {
  return __builtin_nontemporal_load(reinterpret_cast<const f32x4*>(p));
}

// Pack W into MFMA-B fragment order: elem idx = ((kF*4 + ct)*64 + lane)*8 + i
// holds W[Fk = (kF&15)*32 + (lane>>4)*8 + i][c = ct*16 + (lane&15)], section kF>>4:
//   0: w1 = -0.5*(exp(-lv)-1)   (vs xx, centered variance term)
//   1: wh = f16(mu*exp(-lv))    (vs xh and xl)
//   2: wl = residual of wh      (vs xh)
__global__ __launch_bounds__(256) void fill_w(const float* __restrict__ mu,
                                              const float* __restrict__ lv,
                                              f16* __restrict__ wfrag) {
  int idx = blockIdx.x * 256 + threadIdx.x;
  int i = idx & 7, l = (idx >> 3) & 63, ct = (idx >> 9) & 3, kF = idx >> 11;
  int k = (kF & 15) * 32 + (l >> 4) * 8 + i;
  int c = ct * 16 + (l & 15);
  int sec = kF >> 4;
  float lvv = lv[c * KK + k];
  float w;
  if (sec == 0) {
    w = -0.5f * expm1f(-lvv);
  } else {
    float w2 = mu[c * KK + k] * expf(-lvv);
    float wh = (float)(f16)w2;
    w = (sec == 1) ? wh : (w2 - wh);
  }
  wfrag[idx] = (f16)w;
}

// bias[j][c] = log(alpha*beta[c] + njk[j][c]) - 0.5*(sum_k(mu^2*iv + lv) + K*ln(2pi))
__global__ __launch_bounds__(64) void fill_bias(const float* __restrict__ mu,
                                                const float* __restrict__ lv,
                                                const float* __restrict__ beta,
                                                const float* __restrict__ njk,
                                                const float* __restrict__ alphap,
                                                float* __restrict__ bias) {
  int c = blockIdx.x;
  int lane = threadIdx.x;
  float s = 0.0f;
  for (int k = lane; k < KK; k += 64) {
    float l2 = lv[c * KK + k];
    float m = mu[c * KK + k];
    s += fmaf(m * m, expf(-l2), l2);
  }
  #pragma unroll
  for (int d = 1; d < 64; d <<= 1) s += __shfl_xor(s, d, 64);
  float base = -0.5f * (s + 512.0f * 1.8378770664093453f);
  if (lane < JJ)
    bias[lane * CC + c] = logf(alphap[0] * beta[c] + njk[lane * CC + c]) + base;
}

// DIAGNOSTIC build of the R3 kernel (best: 129.8 us): identical dataflow,
// wrapped in REPS=3 idempotent repeats so the dispatch exceeds the harness
// poison-fills and surfaces full rocprof counters for this kernel.
// 4-wave wg, 128 rows/wg. LDS double-buffered W staging, plain __syncthreads.
// Layouts (m89-verified): A row=l&15, k=(l>>4)*8+i; D col=l&15, row=(l>>4)*4+reg.
__global__ __launch_bounds__(256, 3) void gmm_main(
    const float* __restrict__ x, const int* __restrict__ ms,
    const f16* __restrict__ wfrag, const float* __restrict__ bias,
    float* __restrict__ out) {
  __shared__ char lds[2 * 12288];
  const int t = threadIdx.x;
  const int lane = t & 63;
  const int wv = t >> 6;
  const int lr = lane & 15;   // A row / D col / B col within tile
  const int kg = lane >> 4;   // k-group (8 consecutive k each)
  const long row0 = (long)blockIdx.x * 128 + wv * 32;
  const bool valid = row0 < NN;            // last wg: invalid waves stay for barriers
  const long r0 = valid ? row0 + lr : 0;
  const long r1 = valid ? row0 + 16 + lr : 0;

  const float* xp0 = x + r0 * KK + kg * 8;
  const float* xp1 = x + r1 * KK + kg * 8;
  const char* wfb = (const char*)wfrag;
  const int lsec = wv * 1024 + lane * 16;  // 16B slot within a 4 KiB sec-chunk

  #pragma unroll 1
  for (int rep = 0; rep < REPS; ++rep) {
    f32x4 acc[2][4];
    #pragma unroll
    for (int rt = 0; rt < 2; ++rt)
      #pragma unroll
      for (int ct = 0; ct < 4; ++ct) acc[rt][ct] = (f32x4)0.0f;

    // prologue: stage s=0 into buf0; load s=0 x
    #pragma unroll
    for (int sec = 0; sec < 3; ++sec)
      gload_lds16(wfb + sec * 65536 + lsec, lds + sec * 4096 + wv * 1024);

    f32x4 cx[4];
    cx[0] = ntl(xp0);
    cx[1] = ntl(xp0 + 4);
    cx[2] = ntl(xp1);
    cx[3] = ntl(xp1 + 4);
    __syncthreads();

    int cur = 0;
    #pragma unroll 1
    for (int s = 0; s < 16; ++s) {
      // stage s+1 into the other buffer; prefetch next x
      f32x4 nx[4];
      if (s < 15) {
        const char* gsrc = wfb + (s + 1) * 4096;
        char* ldst = lds + (cur ^ 1) * 12288;
        #pragma unroll
        for (int sec = 0; sec < 3; ++sec)
          gload_lds16(gsrc + sec * 65536 + lsec, ldst + sec * 4096 + wv * 1024);
        const float* p0 = xp0 + (s + 1) * 32;
        const float* p1 = xp1 + (s + 1) * 32;
        nx[0] = ntl(p0);
        nx[1] = ntl(p0 + 4);
        nx[2] = ntl(p1);
        nx[3] = ntl(p1 + 4);
      }

      // convert current x to f16 hi/lo/square fragments
      f16x8 fxx[2], fxh[2], fxl[2];
      #pragma unroll
      for (int rt = 0; rt < 2; ++rt) {
        #pragma unroll
        for (int i = 0; i < 8; ++i) {
          float v = (i < 4) ? cx[rt * 2][i] : cx[rt * 2 + 1][i - 4];
          f16 h = (f16)v;
          fxh[rt][i] = h;
          fxl[rt][i] = (f16)(v - (float)h);
          fxx[rt][i] = (f16)(v * v);
        }
      }

      // B-frags from LDS (16B/lane contiguous -> conflict-free ds_read_b128)
      const f16* lbase = (const f16*)(lds + cur * 12288) + lane * 8;
      #pragma unroll
      for (int ct = 0; ct < 4; ++ct) {
        f16x8 bw1 = *reinterpret_cast<const f16x8*>(lbase + ct * 512);
        f16x8 bwh = *reinterpret_cast<const f16x8*>(lbase + 2048 + ct * 512);
        f16x8 bwl = *reinterpret_cast<const f16x8*>(lbase + 4096 + ct * 512);
        #pragma unroll
        for (int rt = 0; rt < 2; ++rt) {
          acc[rt][ct] = __builtin_amdgcn_mfma_f32_16x16x32_f16(fxx[rt], bw1, acc[rt][ct], 0, 0, 0);
          acc[rt][ct] = __builtin_amdgcn_mfma_f32_16x16x32_f16(fxh[rt], bwh, acc[rt][ct], 0, 0, 0);
          acc[rt][ct] = __builtin_amdgcn_mfma_f32_16x16x32_f16(fxh[rt], bwl, acc[rt][ct], 0, 0, 0);
          acc[rt][ct] = __builtin_amdgcn_mfma_f32_16x16x32_f16(fxl[rt], bwh, acc[rt][ct], 0, 0, 0);
        }
      }

      __syncthreads();  // staged buf complete + all reads of cur done
      cur ^= 1;
      if (s < 15) {
        cx[0] = nx[0]; cx[1] = nx[1]; cx[2] = nx[2]; cx[3] = nx[3];
      }
    }

    // Epilogue: bias add + softmax across 64 cols (4 regs x 16 lanes) + store.
    if (valid) {
      #pragma unroll
      for (int rt = 0; rt < 2; ++rt) {
        long rbase = row0 + rt * 16 + kg * 4;
        #pragma unroll
        for (int r = 0; r < 4; ++r) {
          int j = ms[rbase + r];
          const float* bj = bias + j * CC + lr;
          float v0 = acc[rt][0][r] + bj[0];
          float v1 = acc[rt][1][r] + bj[16];
          float v2 = acc[rt][2][r] + bj[32];
          float v3 = acc[rt][3][r] + bj[48];
          float m = fmaxf(fmaxf(v0, v1), fmaxf(v2, v3));
          #pragma unroll
          for (int d = 1; d < 16; d <<= 1) m = fmaxf(m, __shfl_xor(m, d, 64));
          float e0 = __expf(v0 - m), e1 = __expf(v1 - m);
          float e2 = __expf(v2 - m), e3 = __expf(v3 - m);
          float sum = (e0 + e1) + (e2 + e3);
          #pragma unroll
          for (int d = 1; d < 16; d <<= 1) sum += __shfl_xor(sum, d, 64);
          float inv = 1.0f / sum;
          float* o = out + (size_t)rbase * CC + r * CC + lr;
          __builtin_nontemporal_store(e0 * inv, o);
          __builtin_nontemporal_store(e1 * inv, o + 16);
          __builtin_nontemporal_store(e2 * inv, o + 32);
          __builtin_nontemporal_store(e3 * inv, o + 48);
        }
      }
    }
    __syncthreads();  // rep boundary: all reads done before next rep restages buf0
  }
}

extern "C" void kernel_launch(void* const* d_in, const int* in_sizes, int n_in,
                              void* d_out, int out_size, void* d_ws, size_t ws_size,
                              hipStream_t stream) {
  const float* x     = (const float*)d_in[0];
  const float* mu    = (const float*)d_in[1];
  const float* lv    = (const float*)d_in[2];
  const float* beta  = (const float*)d_in[3];
  const float* njk   = (const float*)d_in[4];
  const float* alpha = (const float*)d_in[5];
  const int*   ms    = (const int*)d_in[6];
  float* out = (float*)d_out;

  f16* wfrag  = (f16*)d_ws;
  float* bias = (float*)((char*)d_ws + WFRAG_ELEMS * sizeof(f16));

  fill_w<<<WFRAG_ELEMS / 256, 256, 0, stream>>>(mu, lv, wfrag);
  fill_bias<<<CC, 64, 0, stream>>>(mu, lv, beta, njk, alpha, bias);
  gmm_main<<<(NN + 127) / 128, 256, 0, stream>>>(x, ms, wfrag, bias, out);
}

// Round 7
// 148.812 us; speedup vs baseline: 2.3759x; 2.3759x over previous
//
#include <hip/hip_runtime.h>
#include <hip/hip_bf16.h>

typedef _Float16 f16;
typedef _Float16 f16x8 __attribute__((ext_vector_type(8)));
typedef float f32x4 __attribute__((ext_vector_type(4)));

#define NN 200000
#define KK 512
#define CC 64
#define JJ 32
// W_frag: 48 F-ksteps (16 w1 | 16 wh | 16 wl) x 4 coltiles x 64 lanes x 8 f16
#define WFRAG_ELEMS (48 * 4 * 64 * 8) /* 98304 f16 = 192 KiB */

__device__ inline f32x4 ntl(const float* p) {
  return __builtin_nontemporal_load(reinterpret_cast<const f32x4*>(p));
}

// Pack W into MFMA-B fragment order: elem idx = ((kF*4 + ct)*64 + lane)*8 + i
// holds W[Fk = (kF&15)*32 + (lane>>4)*8 + i][c = ct*16 + (lane&15)], section kF>>4:
//   0: w1 = -0.5*(exp(-lv)-1)   (vs xx, centered variance term)
//   1: wh = f16(mu*exp(-lv))    (vs xh and xl)
//   2: wl = residual of wh      (vs xh)
__global__ __launch_bounds__(256) void fill_w(const float* __restrict__ mu,
                                              const float* __restrict__ lv,
                                              f16* __restrict__ wfrag) {
  int idx = blockIdx.x * 256 + threadIdx.x;
  int i = idx & 7, l = (idx >> 3) & 63, ct = (idx >> 9) & 3, kF = idx >> 11;
  int k = (kF & 15) * 32 + (l >> 4) * 8 + i;
  int c = ct * 16 + (l & 15);
  int sec = kF >> 4;
  float lvv = lv[c * KK + k];
  float w;
  if (sec == 0) {
    w = -0.5f * expm1f(-lvv);
  } else {
    float w2 = mu[c * KK + k] * expf(-lvv);
    float wh = (float)(f16)w2;
    w = (sec == 1) ? wh : (w2 - wh);
  }
  wfrag[idx] = (f16)w;
}

// bias[j][c] = log(alpha*beta[c] + njk[j][c]) - 0.5*(sum_k(mu^2*iv + lv) + K*ln(2pi))
__global__ __launch_bounds__(64) void fill_bias(const float* __restrict__ mu,
                                                const float* __restrict__ lv,
                                                const float* __restrict__ beta,
                                                const float* __restrict__ njk,
                                                const float* __restrict__ alphap,
                                                float* __restrict__ bias) {
  int c = blockIdx.x;
  int lane = threadIdx.x;
  float s = 0.0f;
  for (int k = lane; k < KK; k += 64) {
    float l2 = lv[c * KK + k];
    float m = mu[c * KK + k];
    s += fmaf(m * m, expf(-l2), l2);
  }
  #pragma unroll
  for (int d = 1; d < 64; d <<= 1) s += __shfl_xor(s, d, 64);
  float base = -0.5f * (s + 512.0f * 1.8378770664093453f);
  if (lane < JJ)
    bias[lane * CC + c] = logf(alphap[0] * beta[c] + njk[lane * CC + c]) + base;
}

// Barrier-free rt=4: one wave per 64 rows (grid 3125, exact). No LDS. W-frags
// read directly from L2 (192 KiB hot, 600 MB total = ~75 MB/XCD). x prefetched
// 1 step ahead into the just-consumed registers; prefetch issued BEFORE the
// step's W loads so x stays in flight across the MFMA block (vmcnt ordering).
// Layouts (m89-verified): A row=l&15, k=(l>>4)*8+i; D col=l&15, row=(l>>4)*4+reg.
__global__ __launch_bounds__(64, 3) void gmm_main(
    const float* __restrict__ x, const int* __restrict__ ms,
    const f16* __restrict__ wfrag, const float* __restrict__ bias,
    float* __restrict__ out) {
  const int lane = threadIdx.x;
  const int lr = lane & 15;   // A row / D col / B col within tile
  const int kg = lane >> 4;   // k-group (8 consecutive k each)
  const long row0 = (long)blockIdx.x * 64;

  const float* xp0 = x + (row0 + 0 * 16 + lr) * KK + kg * 8;
  const float* xp1 = x + (row0 + 1 * 16 + lr) * KK + kg * 8;
  const float* xp2 = x + (row0 + 2 * 16 + lr) * KK + kg * 8;
  const float* xp3 = x + (row0 + 3 * 16 + lr) * KK + kg * 8;
  const f16* wb = wfrag + lane * 8;

  f32x4 acc[4][4];  // [rt][ct]
  #pragma unroll
  for (int rt = 0; rt < 4; ++rt)
    #pragma unroll
    for (int ct = 0; ct < 4; ++ct) acc[rt][ct] = (f32x4)0.0f;

  // cx[rt*2], cx[rt*2+1] = 8 floats of row-tile rt for the current step
  f32x4 cx[8];
  cx[0] = ntl(xp0); cx[1] = ntl(xp0 + 4);
  cx[2] = ntl(xp1); cx[3] = ntl(xp1 + 4);
  cx[4] = ntl(xp2); cx[5] = ntl(xp2 + 4);
  cx[6] = ntl(xp3); cx[7] = ntl(xp3 + 4);

  #pragma unroll 1
  for (int s = 0; s < 16; ++s) {
    // (a) convert current x to f16 hi/lo/square fragments (cx dead after)
    f16x8 fxx[4], fxh[4], fxl[4];
    #pragma unroll
    for (int rt = 0; rt < 4; ++rt) {
      #pragma unroll
      for (int i = 0; i < 8; ++i) {
        float v = (i < 4) ? cx[rt * 2][i] : cx[rt * 2 + 1][i - 4];
        f16 h = (f16)v;
        fxh[rt][i] = h;
        fxl[rt][i] = (f16)(v - (float)h);
        fxx[rt][i] = (f16)(v * v);
      }
    }
    // (b) prefetch x(s+1) into cx (issued before W loads -> stays in flight
    //     across the whole MFMA block; consumed only at next convert)
    if (s < 15) {
      const int o = (s + 1) * 32;
      cx[0] = ntl(xp0 + o); cx[1] = ntl(xp0 + o + 4);
      cx[2] = ntl(xp1 + o); cx[3] = ntl(xp1 + o + 4);
      cx[4] = ntl(xp2 + o); cx[5] = ntl(xp2 + o + 4);
      cx[6] = ntl(xp3 + o); cx[7] = ntl(xp3 + o + 4);
    }
    // (c) per col-tile: 3 W-frag loads (L2-hot) + 16 MFMAs
    const f16* wbs = wb + (size_t)s * 2048;
    #pragma unroll
    for (int ct = 0; ct < 4; ++ct) {
      f16x8 bw1 = *reinterpret_cast<const f16x8*>(wbs + ct * 512);
      f16x8 bwh = *reinterpret_cast<const f16x8*>(wbs + 32768 + ct * 512);
      f16x8 bwl = *reinterpret_cast<const f16x8*>(wbs + 65536 + ct * 512);
      #pragma unroll
      for (int rt = 0; rt < 4; ++rt) {
        acc[rt][ct] = __builtin_amdgcn_mfma_f32_16x16x32_f16(fxx[rt], bw1, acc[rt][ct], 0, 0, 0);
        acc[rt][ct] = __builtin_amdgcn_mfma_f32_16x16x32_f16(fxh[rt], bwh, acc[rt][ct], 0, 0, 0);
        acc[rt][ct] = __builtin_amdgcn_mfma_f32_16x16x32_f16(fxh[rt], bwl, acc[rt][ct], 0, 0, 0);
        acc[rt][ct] = __builtin_amdgcn_mfma_f32_16x16x32_f16(fxl[rt], bwh, acc[rt][ct], 0, 0, 0);
      }
    }
  }

  // Epilogue: bias add + softmax across 64 cols (4 regs x 16 lanes) + store.
  #pragma unroll
  for (int rt = 0; rt < 4; ++rt) {
    long rbase = row0 + rt * 16 + kg * 4;
    #pragma unroll
    for (int r = 0; r < 4; ++r) {
      int j = ms[rbase + r];
      const float* bj = bias + j * CC + lr;
      float v0 = acc[rt][0][r] + bj[0];
      float v1 = acc[rt][1][r] + bj[16];
      float v2 = acc[rt][2][r] + bj[32];
      float v3 = acc[rt][3][r] + bj[48];
      float m = fmaxf(fmaxf(v0, v1), fmaxf(v2, v3));
      #pragma unroll
      for (int d = 1; d < 16; d <<= 1) m = fmaxf(m, __shfl_xor(m, d, 64));
      float e0 = __expf(v0 - m), e1 = __expf(v1 - m);
      float e2 = __expf(v2 - m), e3 = __expf(v3 - m);
      float sum = (e0 + e1) + (e2 + e3);
      #pragma unroll
      for (int d = 1; d < 16; d <<= 1) sum += __shfl_xor(sum, d, 64);
      float inv = 1.0f / sum;
      float* o = out + (size_t)(rbase + r) * CC + lr;
      __builtin_nontemporal_store(e0 * inv, o);
      __builtin_nontemporal_store(e1 * inv, o + 16);
      __builtin_nontemporal_store(e2 * inv, o + 32);
      __builtin_nontemporal_store(e3 * inv, o + 48);
    }
  }
}

extern "C" void kernel_launch(void* const* d_in, const int* in_sizes, int n_in,
                              void* d_out, int out_size, void* d_ws, size_t ws_size,
                              hipStream_t stream) {
  const float* x     = (const float*)d_in[0];
  const float* mu    = (const float*)d_in[1];
  const float* lv    = (const float*)d_in[2];
  const float* beta  = (const float*)d_in[3];
  const float* njk   = (const float*)d_in[4];
  const float* alpha = (const float*)d_in[5];
  const int*   ms    = (const int*)d_in[6];
  float* out = (float*)d_out;

  f16* wfrag  = (f16*)d_ws;
  float* bias = (float*)((char*)d_ws + WFRAG_ELEMS * sizeof(f16));

  fill_w<<<WFRAG_ELEMS / 256, 256, 0, stream>>>(mu, lv, wfrag);
  fill_bias<<<CC, 64, 0, stream>>>(mu, lv, beta, njk, alpha, bias);
  gmm_main<<<NN / 64, 64, 0, stream>>>(x, ms, wfrag, bias, out);
}

// Round 8
// 134.563 us; speedup vs baseline: 2.6275x; 1.1059x over previous
//
#include <hip/hip_runtime.h>
#include <hip/hip_bf16.h>

typedef _Float16 f16;
typedef _Float16 f16x8 __attribute__((ext_vector_type(8)));
typedef float f32x4 __attribute__((ext_vector_type(4)));

#define NN 200000
#define KK 512
#define CC 64
#define JJ 32
// W_frag: 48 F-ksteps (16 w1 | 16 wh | 16 wl) x 4 coltiles x 64 lanes x 8 f16
#define WFRAG_ELEMS (48 * 4 * 64 * 8) /* 98304 f16 = 192 KiB */

__device__ inline void gload_lds16(const void* g, void* l) {
  __builtin_amdgcn_global_load_lds(
      (const __attribute__((address_space(1))) void*)g,
      (__attribute__((address_space(3))) void*)l, 16, 0, 0);
}

__device__ inline f32x4 ntl(const float* p) {
  return __builtin_nontemporal_load(reinterpret_cast<const f32x4*>(p));
}

// Pack W into MFMA-B fragment order: elem idx = ((kF*4 + ct)*64 + lane)*8 + i
// holds W[Fk = (kF&15)*32 + (lane>>4)*8 + i][c = ct*16 + (lane&15)], section kF>>4:
//   0: w1 = -0.5*(exp(-lv)-1)   (vs xx, centered variance term)
//   1: wh = f16(mu*exp(-lv))    (vs xh and xl)
//   2: wl = residual of wh      (vs xh)
__global__ __launch_bounds__(256) void fill_w(const float* __restrict__ mu,
                                              const float* __restrict__ lv,
                                              f16* __restrict__ wfrag) {
  int idx = blockIdx.x * 256 + threadIdx.x;
  int i = idx & 7, l = (idx >> 3) & 63, ct = (idx >> 9) & 3, kF = idx >> 11;
  int k = (kF & 15) * 32 + (l >> 4) * 8 + i;
  int c = ct * 16 + (l & 15);
  int sec = kF >> 4;
  float lvv = lv[c * KK + k];
  float w;
  if (sec == 0) {
    w = -0.5f * expm1f(-lvv);
  } else {
    float w2 = mu[c * KK + k] * expf(-lvv);
    float wh = (float)(f16)w2;
    w = (sec == 1) ? wh : (w2 - wh);
  }
  wfrag[idx] = (f16)w;
}

// bias[j][c] = log(alpha*beta[c] + njk[j][c]) - 0.5*(sum_k(mu^2*iv + lv) + K*ln(2pi))
__global__ __launch_bounds__(64) void fill_bias(const float* __restrict__ mu,
                                                const float* __restrict__ lv,
                                                const float* __restrict__ beta,
                                                const float* __restrict__ njk,
                                                const float* __restrict__ alphap,
                                                float* __restrict__ bias) {
  int c = blockIdx.x;
  int lane = threadIdx.x;
  float s = 0.0f;
  for (int k = lane; k < KK; k += 64) {
    float l2 = lv[c * KK + k];
    float m = mu[c * KK + k];
    s += fmaf(m * m, expf(-l2), l2);
  }
  #pragma unroll
  for (int d = 1; d < 64; d <<= 1) s += __shfl_xor(s, d, 64);
  float base = -0.5f * (s + 512.0f * 1.8378770664093453f);
  if (lane < JJ)
    bias[lane * CC + c] = logf(alphap[0] * beta[c] + njk[lane * CC + c]) + base;
}

// 8-wave workgroup (512 thr), 256 rows/wg, 32 rows/wave — R3 dataflow with
// more waves per LDS allocation (occupancy was block-residency-limited: R6
// showed 28% occupancy at 24.6KB/4-wave blocks). W staging split as 12x1KB
// chunks over 8 waves; W L2 traffic halves to ~150MB.
// Layouts (m89-verified): A row=l&15, k=(l>>4)*8+i; D col=l&15, row=(l>>4)*4+reg.
__global__ __launch_bounds__(512, 4) void gmm_main(
    const float* __restrict__ x, const int* __restrict__ ms,
    const f16* __restrict__ wfrag, const float* __restrict__ bias,
    float* __restrict__ out) {
  __shared__ char lds[2 * 12288];
  const int t = threadIdx.x;
  const int lane = t & 63;
  const int wv = t >> 6;                   // 0..7
  const int lr = lane & 15;   // A row / D col / B col within tile
  const int kg = lane >> 4;   // k-group (8 consecutive k each)
  const long row0 = (long)blockIdx.x * 256 + wv * 32;
  const bool valid = row0 < NN;            // NN%32==0: valid => all 32 rows valid
  const long r0 = valid ? row0 + lr : 0;
  const long r1 = valid ? row0 + 16 + lr : 0;

  const float* xp0 = x + r0 * KK + kg * 8;
  const float* xp1 = x + r1 * KK + kg * 8;
  const char* wfb = (const char*)wfrag;

  // staging chunk assignment: 12 chunks of 1KB (sec=c>>2, part=c&3);
  // wave w stages chunk w, and w+8 if w<4. Wave-uniform LDS base (HW adds
  // lane*16); per-lane global addr carries lane*16.
  const int c0 = wv, c1 = wv + 8;
  const int c0_l = (c0 >> 2) * 4096 + (c0 & 3) * 1024;
  const int c0_g = (c0 >> 2) * 65536 + (c0 & 3) * 1024 + lane * 16;
  const int c1_l = (c1 >> 2) * 4096 + (c1 & 3) * 1024;
  const int c1_g = (c1 >> 2) * 65536 + (c1 & 3) * 1024 + lane * 16;

  auto stage = [&](int sn, int buf) {
    gload_lds16(wfb + sn * 4096 + c0_g, lds + buf * 12288 + c0_l);
    if (wv < 4)
      gload_lds16(wfb + sn * 4096 + c1_g, lds + buf * 12288 + c1_l);
  };

  f32x4 acc[2][4];
  #pragma unroll
  for (int rt = 0; rt < 2; ++rt)
    #pragma unroll
    for (int ct = 0; ct < 4; ++ct) acc[rt][ct] = (f32x4)0.0f;

  // prologue: stage s=0 into buf0; load s=0 x
  stage(0, 0);
  f32x4 cx[4];
  cx[0] = ntl(xp0);
  cx[1] = ntl(xp0 + 4);
  cx[2] = ntl(xp1);
  cx[3] = ntl(xp1 + 4);
  __syncthreads();

  int cur = 0;
  #pragma unroll 1
  for (int s = 0; s < 16; ++s) {
    // stage s+1 into the other buffer; prefetch next x
    f32x4 nx[4];
    if (s < 15) {
      stage(s + 1, cur ^ 1);
      const float* p0 = xp0 + (s + 1) * 32;
      const float* p1 = xp1 + (s + 1) * 32;
      nx[0] = ntl(p0);
      nx[1] = ntl(p0 + 4);
      nx[2] = ntl(p1);
      nx[3] = ntl(p1 + 4);
    }

    // convert current x to f16 hi/lo/square fragments
    f16x8 fxx[2], fxh[2], fxl[2];
    #pragma unroll
    for (int rt = 0; rt < 2; ++rt) {
      #pragma unroll
      for (int i = 0; i < 8; ++i) {
        float v = (i < 4) ? cx[rt * 2][i] : cx[rt * 2 + 1][i - 4];
        f16 h = (f16)v;
        fxh[rt][i] = h;
        fxl[rt][i] = (f16)(v - (float)h);
        fxx[rt][i] = (f16)(v * v);
      }
    }

    // B-frags from LDS (16B/lane contiguous -> conflict-free ds_read_b128)
    const f16* lbase = (const f16*)(lds + cur * 12288) + lane * 8;
    #pragma unroll
    for (int ct = 0; ct < 4; ++ct) {
      f16x8 bw1 = *reinterpret_cast<const f16x8*>(lbase + ct * 512);
      f16x8 bwh = *reinterpret_cast<const f16x8*>(lbase + 2048 + ct * 512);
      f16x8 bwl = *reinterpret_cast<const f16x8*>(lbase + 4096 + ct * 512);
      #pragma unroll
      for (int rt = 0; rt < 2; ++rt) {
        acc[rt][ct] = __builtin_amdgcn_mfma_f32_16x16x32_f16(fxx[rt], bw1, acc[rt][ct], 0, 0, 0);
        acc[rt][ct] = __builtin_amdgcn_mfma_f32_16x16x32_f16(fxh[rt], bwh, acc[rt][ct], 0, 0, 0);
        acc[rt][ct] = __builtin_amdgcn_mfma_f32_16x16x32_f16(fxh[rt], bwl, acc[rt][ct], 0, 0, 0);
        acc[rt][ct] = __builtin_amdgcn_mfma_f32_16x16x32_f16(fxl[rt], bwh, acc[rt][ct], 0, 0, 0);
      }
    }

    __syncthreads();  // staged buf complete + all reads of cur done
    cur ^= 1;
    if (s < 15) {
      cx[0] = nx[0]; cx[1] = nx[1]; cx[2] = nx[2]; cx[3] = nx[3];
    }
  }

  // Epilogue: bias add + softmax across 64 cols (4 regs x 16 lanes) + store.
  if (valid) {
    #pragma unroll
    for (int rt = 0; rt < 2; ++rt) {
      long rbase = row0 + rt * 16 + kg * 4;
      #pragma unroll
      for (int r = 0; r < 4; ++r) {
        int j = ms[rbase + r];
        const float* bj = bias + j * CC + lr;
        float v0 = acc[rt][0][r] + bj[0];
        float v1 = acc[rt][1][r] + bj[16];
        float v2 = acc[rt][2][r] + bj[32];
        float v3 = acc[rt][3][r] + bj[48];
        float m = fmaxf(fmaxf(v0, v1), fmaxf(v2, v3));
        #pragma unroll
        for (int d = 1; d < 16; d <<= 1) m = fmaxf(m, __shfl_xor(m, d, 64));
        float e0 = __expf(v0 - m), e1 = __expf(v1 - m);
        float e2 = __expf(v2 - m), e3 = __expf(v3 - m);
        float sum = (e0 + e1) + (e2 + e3);
        #pragma unroll
        for (int d = 1; d < 16; d <<= 1) sum += __shfl_xor(sum, d, 64);
        float inv = 1.0f / sum;
        float* o = out + (size_t)(rbase + r) * CC + lr;
        __builtin_nontemporal_store(e0 * inv, o);
        __builtin_nontemporal_store(e1 * inv, o + 16);
        __builtin_nontemporal_store(e2 * inv, o + 32);
        __builtin_nontemporal_store(e3 * inv, o + 48);
      }
    }
  }
}

extern "C" void kernel_launch(void* const* d_in, const int* in_sizes, int n_in,
                              void* d_out, int out_size, void* d_ws, size_t ws_size,
                              hipStream_t stream) {
  const float* x     = (const float*)d_in[0];
  const float* mu    = (const float*)d_in[1];
  const float* lv    = (const float*)d_in[2];
  const float* beta  = (const float*)d_in[3];
  const float* njk   = (const float*)d_in[4];
  const float* alpha = (const float*)d_in[5];
  const int*   ms    = (const int*)d_in[6];
  float* out = (float*)d_out;

  f16* wfrag  = (f16*)d_ws;
  float* bias = (float*)((char*)d_ws + WFRAG_ELEMS * sizeof(f16));

  fill_w<<<WFRAG_ELEMS / 256, 256, 0, stream>>>(mu, lv, wfrag);
  fill_bias<<<CC, 64, 0, stream>>>(mu, lv, beta, njk, alpha, bias);
  gmm_main<<<(NN + 255) / 256, 512, 0, stream>>>(x, ms, wfrag, bias, out);
}

// Round 9
// 132.119 us; speedup vs baseline: 2.6761x; 1.0185x over previous
//
#include <hip/hip_runtime.h>
#include <hip/hip_bf16.h>

typedef _Float16 f16;
typedef _Float16 f16x8 __attribute__((ext_vector_type(8)));
typedef float f32x4 __attribute__((ext_vector_type(4)));

#define NN 200000
#define KK 512
#define CC 64
#define JJ 32
// W_frag: 48 F-ksteps (16 w1 | 16 wh | 16 wl) x 4 coltiles x 64 lanes x 8 f16
#define WFRAG_ELEMS (48 * 4 * 64 * 8) /* 98304 f16 = 192 KiB */

__device__ inline void gload_lds16(const void* g, void* l) {
  __builtin_amdgcn_global_load_lds(
      (const __attribute__((address_space(1))) void*)g,
      (__attribute__((address_space(3))) void*)l, 16, 0, 0);
}

__device__ inline f32x4 ntl(const float* p) {
  return __builtin_nontemporal_load(reinterpret_cast<const f32x4*>(p));
}

// Pack W into MFMA-B fragment order: elem idx = ((kF*4 + ct)*64 + lane)*8 + i
// holds W[Fk = (kF&15)*32 + (lane>>4)*8 + i][c = ct*16 + (lane&15)], section kF>>4:
//   0: w1 = -0.5*(exp(-lv)-1)   (vs xx, centered variance term)
//   1: wh = f16(mu*exp(-lv))    (vs xh and xl)
//   2: wl = residual of wh      (vs xh)
__global__ __launch_bounds__(256) void fill_w(const float* __restrict__ mu,
                                              const float* __restrict__ lv,
                                              f16* __restrict__ wfrag) {
  int idx = blockIdx.x * 256 + threadIdx.x;
  int i = idx & 7, l = (idx >> 3) & 63, ct = (idx >> 9) & 3, kF = idx >> 11;
  int k = (kF & 15) * 32 + (l >> 4) * 8 + i;
  int c = ct * 16 + (l & 15);
  int sec = kF >> 4;
  float lvv = lv[c * KK + k];
  float w;
  if (sec == 0) {
    w = -0.5f * expm1f(-lvv);
  } else {
    float w2 = mu[c * KK + k] * expf(-lvv);
    float wh = (float)(f16)w2;
    w = (sec == 1) ? wh : (w2 - wh);
  }
  wfrag[idx] = (f16)w;
}

// bias[j][c] = log(alpha*beta[c] + njk[j][c]) - 0.5*(sum_k(mu^2*iv + lv) + K*ln(2pi))
__global__ __launch_bounds__(64) void fill_bias(const float* __restrict__ mu,
                                                const float* __restrict__ lv,
                                                const float* __restrict__ beta,
                                                const float* __restrict__ njk,
                                                const float* __restrict__ alphap,
                                                float* __restrict__ bias) {
  int c = blockIdx.x;
  int lane = threadIdx.x;
  float s = 0.0f;
  for (int k = lane; k < KK; k += 64) {
    float l2 = lv[c * KK + k];
    float m = mu[c * KK + k];
    s += fmaf(m * m, expf(-l2), l2);
  }
  #pragma unroll
  for (int d = 1; d < 64; d <<= 1) s += __shfl_xor(s, d, 64);
  float base = -0.5f * (s + 512.0f * 1.8378770664093453f);
  if (lane < JJ)
    bias[lane * CC + c] = logf(alphap[0] * beta[c] + njk[lane * CC + c]) + base;
}

// BK=64: 8 barrier phases per tile (was 16). Per phase: stage 24KB W chunk
// (2 k-steps x 3 sections) into the alternate LDS buffer, prefetch both x
// slabs for the next phase in one burst, compute 2 k-steps (32 MFMAs), ONE
// __syncthreads. Halves the count of synchronized drain points; x gets a
// full phase of latency cover. Numerics identical to R3 (s-sequential).
// Layouts (m89-verified): A row=l&15, k=(l>>4)*8+i; D col=l&15, row=(l>>4)*4+reg.
__global__ __launch_bounds__(256, 3) void gmm_main(
    const float* __restrict__ x, const int* __restrict__ ms,
    const f16* __restrict__ wfrag, const float* __restrict__ bias,
    float* __restrict__ out) {
  __shared__ char lds[2 * 24576];
  const int t = threadIdx.x;
  const int lane = t & 63;
  const int wv = t >> 6;
  const int lr = lane & 15;   // A row / D col / B col within tile
  const int kg = lane >> 4;   // k-group (8 consecutive k each)
  const long row0 = (long)blockIdx.x * 128 + wv * 32;
  const bool valid = row0 < NN;            // NN%32==0: valid => all 32 rows valid
  const long r0 = valid ? row0 + lr : 0;
  const long r1 = valid ? row0 + 16 + lr : 0;

  const float* xp0 = x + r0 * KK + kg * 8;
  const float* xp1 = x + r1 * KK + kg * 8;
  const char* wfb = (const char*)wfrag;
  const int lsec = wv * 1024 + lane * 16;  // slot within a 4 KiB chunk

  // stage phase pn (k-steps 2pn, 2pn+1) into buffer b: 6 x 4KB chunks
  auto stage = [&](int pn, int b) {
    #pragma unroll
    for (int sec = 0; sec < 3; ++sec)
      #pragma unroll
      for (int q = 0; q < 2; ++q)
        gload_lds16(wfb + sec * 65536 + (pn * 2 + q) * 4096 + lsec,
                    lds + b * 24576 + sec * 8192 + q * 4096 + wv * 1024);
  };

  f32x4 acc[2][4];
  #pragma unroll
  for (int rt = 0; rt < 2; ++rt)
    #pragma unroll
    for (int ct = 0; ct < 4; ++ct) acc[rt][ct] = (f32x4)0.0f;

  // x slabs: cxA = even k-step of current phase, cxB = odd k-step
  f32x4 cxA[4], cxB[4], nxA[4], nxB[4];

  // prologue: stage phase 0 -> buf0; load x slabs for phase 0
  stage(0, 0);
  cxA[0] = ntl(xp0);      cxA[1] = ntl(xp0 + 4);
  cxA[2] = ntl(xp1);      cxA[3] = ntl(xp1 + 4);
  cxB[0] = ntl(xp0 + 32); cxB[1] = ntl(xp0 + 36);
  cxB[2] = ntl(xp1 + 32); cxB[3] = ntl(xp1 + 36);
  __syncthreads();

  // convert one step's x to f16 frags
  auto convert = [&](const f32x4 (&cx)[4], f16x8 (&fxx)[2], f16x8 (&fxh)[2],
                     f16x8 (&fxl)[2]) {
    #pragma unroll
    for (int rt = 0; rt < 2; ++rt) {
      #pragma unroll
      for (int i = 0; i < 8; ++i) {
        float v = (i < 4) ? cx[rt * 2][i] : cx[rt * 2 + 1][i - 4];
        f16 h = (f16)v;
        fxh[rt][i] = h;
        fxl[rt][i] = (f16)(v - (float)h);
        fxx[rt][i] = (f16)(v * v);
      }
    }
  };

  // MFMA one k-step from LDS buffer b, parity q
  auto mfma_step = [&](int b, int q, const f16x8 (&fxx)[2],
                       const f16x8 (&fxh)[2], const f16x8 (&fxl)[2]) {
    const f16* lbase = (const f16*)(lds + b * 24576 + q * 4096) + lane * 8;
    #pragma unroll
    for (int ct = 0; ct < 4; ++ct) {
      f16x8 bw1 = *reinterpret_cast<const f16x8*>(lbase + ct * 512);
      f16x8 bwh = *reinterpret_cast<const f16x8*>(lbase + 4096 + ct * 512);
      f16x8 bwl = *reinterpret_cast<const f16x8*>(lbase + 8192 + ct * 512);
      #pragma unroll
      for (int rt = 0; rt < 2; ++rt) {
        acc[rt][ct] = __builtin_amdgcn_mfma_f32_16x16x32_f16(fxx[rt], bw1, acc[rt][ct], 0, 0, 0);
        acc[rt][ct] = __builtin_amdgcn_mfma_f32_16x16x32_f16(fxh[rt], bwh, acc[rt][ct], 0, 0, 0);
        acc[rt][ct] = __builtin_amdgcn_mfma_f32_16x16x32_f16(fxh[rt], bwl, acc[rt][ct], 0, 0, 0);
        acc[rt][ct] = __builtin_amdgcn_mfma_f32_16x16x32_f16(fxl[rt], bwh, acc[rt][ct], 0, 0, 0);
      }
    }
  };

  int buf = 0;
  #pragma unroll 1
  for (int p = 0; p < 8; ++p) {
    // prefetch next phase's x slabs FIRST (max drain cover), then stage W
    if (p < 7) {
      const float* q0 = xp0 + (p + 1) * 64;
      const float* q1 = xp1 + (p + 1) * 64;
      nxA[0] = ntl(q0);      nxA[1] = ntl(q0 + 4);
      nxA[2] = ntl(q1);      nxA[3] = ntl(q1 + 4);
      nxB[0] = ntl(q0 + 32); nxB[1] = ntl(q0 + 36);
      nxB[2] = ntl(q1 + 32); nxB[3] = ntl(q1 + 36);
      stage(p + 1, buf ^ 1);
    }

    f16x8 fxx[2], fxh[2], fxl[2];
    convert(cxA, fxx, fxh, fxl);
    mfma_step(buf, 0, fxx, fxh, fxl);
    convert(cxB, fxx, fxh, fxl);
    mfma_step(buf, 1, fxx, fxh, fxl);

    __syncthreads();  // staged buf^1 complete + all reads of buf done
    buf ^= 1;
    if (p < 7) {
      #pragma unroll
      for (int i = 0; i < 4; ++i) { cxA[i] = nxA[i]; cxB[i] = nxB[i]; }
    }
  }

  // Epilogue: bias add + softmax across 64 cols (4 regs x 16 lanes) + store.
  if (valid) {
    #pragma unroll
    for (int rt = 0; rt < 2; ++rt) {
      long rbase = row0 + rt * 16 + kg * 4;
      #pragma unroll
      for (int r = 0; r < 4; ++r) {
        int j = ms[rbase + r];
        const float* bj = bias + j * CC + lr;
        float v0 = acc[rt][0][r] + bj[0];
        float v1 = acc[rt][1][r] + bj[16];
        float v2 = acc[rt][2][r] + bj[32];
        float v3 = acc[rt][3][r] + bj[48];
        float m = fmaxf(fmaxf(v0, v1), fmaxf(v2, v3));
        #pragma unroll
        for (int d = 1; d < 16; d <<= 1) m = fmaxf(m, __shfl_xor(m, d, 64));
        float e0 = __expf(v0 - m), e1 = __expf(v1 - m);
        float e2 = __expf(v2 - m), e3 = __expf(v3 - m);
        float sum = (e0 + e1) + (e2 + e3);
        #pragma unroll
        for (int d = 1; d < 16; d <<= 1) sum += __shfl_xor(sum, d, 64);
        float inv = 1.0f / sum;
        float* o = out + (size_t)(rbase + r) * CC + lr;
        __builtin_nontemporal_store(e0 * inv, o);
        __builtin_nontemporal_store(e1 * inv, o + 16);
        __builtin_nontemporal_store(e2 * inv, o + 32);
        __builtin_nontemporal_store(e3 * inv, o + 48);
      }
    }
  }
}

extern "C" void kernel_launch(void* const* d_in, const int* in_sizes, int n_in,
                              void* d_out, int out_size, void* d_ws, size_t ws_size,
                              hipStream_t stream) {
  const float* x     = (const float*)d_in[0];
  const float* mu    = (const float*)d_in[1];
  const float* lv    = (const float*)d_in[2];
  const float* beta  = (const float*)d_in[3];
  const float* njk   = (const float*)d_in[4];
  const float* alpha = (const float*)d_in[5];
  const int*   ms    = (const int*)d_in[6];
  float* out = (float*)d_out;

  f16* wfrag  = (f16*)d_ws;
  float* bias = (float*)((char*)d_ws + WFRAG_ELEMS * sizeof(f16));

  fill_w<<<WFRAG_ELEMS / 256, 256, 0, stream>>>(mu, lv, wfrag);
  fill_bias<<<CC, 64, 0, stream>>>(mu, lv, beta, njk, alpha, bias);
  gmm_main<<<(NN + 127) / 128, 256, 0, stream>>>(x, ms, wfrag, bias, out);
}